// Round 11
// baseline (522.683 us; speedup 1.0000x reference)
//
#include <hip/hip_runtime.h>
#include <hip/hip_bf16.h>

typedef __bf16 bf16;
typedef __bf16 bf16x4 __attribute__((ext_vector_type(4)));
typedef __bf16 bf16x8 __attribute__((ext_vector_type(8)));
typedef float  f32x4  __attribute__((ext_vector_type(4)));
typedef float  f32x16 __attribute__((ext_vector_type(16)));
typedef unsigned u32x4 __attribute__((ext_vector_type(4)));

#define SEQ  2048
#define HID  4096
#define QKVN 6144   // 4096 Q + 1024 K + 1024 V

__device__ __forceinline__ void gload_lds16(const void* g, void* l) {
  __builtin_amdgcn_global_load_lds(
      (const __attribute__((address_space(1))) void*)g,
      (__attribute__((address_space(3))) void*)l, 16, 0, 0);
}

// v_cvt_pk_bf16_f32: lo -> D[15:0], hi -> D[31:16] (RNE; no builtin on gfx950)
__device__ __forceinline__ unsigned cvtpk(float lo, float hi) {
  unsigned r;
  asm("v_cvt_pk_bf16_f32 %0, %1, %2" : "=v"(r) : "v"(lo), "v"(hi));
  return r;
}
__device__ __forceinline__ void plswap(unsigned& a, unsigned& b) {
  asm("v_permlane32_swap_b32 %0, %1" : "+v"(a), "+v"(b));
}

// ---------------- cast f32 -> bf16 (vectorized) ----------------
__global__ __launch_bounds__(256) void cast_f32_bf16(const float* __restrict__ in,
                                                     bf16* __restrict__ out, int n) {
  int i = (blockIdx.x * 256 + threadIdx.x) * 4;
  int stride = gridDim.x * 256 * 4;
  for (; i < n; i += stride) {
    float4 v = *(const float4*)(in + i);
    bf16x4 o;
    o[0] = (bf16)v.x; o[1] = (bf16)v.y; o[2] = (bf16)v.z; o[3] = (bf16)v.w;
    *(bf16x4*)(out + i) = o;
  }
}

// ---------------- tiled transpose + cast: W[4096][N] f32 -> Wt[roff+N][4096] bf16 ----------------
__global__ __launch_bounds__(256) void transpose_cast(const float* __restrict__ W,
                                                      bf16* __restrict__ Wt,
                                                      int N, int roff) {
  __shared__ float tile[64][65];
  int k0 = blockIdx.y * 64;
  int n0 = blockIdx.x * 64;
  int t = threadIdx.x;
  int lr = t >> 4;            // 0..15
  int lc = (t & 15) * 4;      // 0,4,...,60
#pragma unroll
  for (int p = 0; p < 4; ++p) {
    int row = p * 16 + lr;
    float4 v = *(const float4*)(W + (size_t)(k0 + row) * N + n0 + lc);
    tile[row][lc] = v.x; tile[row][lc + 1] = v.y;
    tile[row][lc + 2] = v.z; tile[row][lc + 3] = v.w;
  }
  __syncthreads();
#pragma unroll
  for (int p = 0; p < 4; ++p) {
    int n = p * 16 + lr;
    bf16x4 o;
#pragma unroll
    for (int q = 0; q < 4; ++q) o[q] = (bf16)tile[lc + q][n];
    *(bf16x4*)(Wt + (size_t)(roff + n0 + n) * 4096 + k0 + lc) = o;
  }
}

// ---------------- transpose V out of QKV into global: Vt_g[g][d][s] ----------------
__global__ __launch_bounds__(256) void transpose_v(const bf16* __restrict__ QKV,
                                                   bf16* __restrict__ Vt_g) {
  __shared__ bf16 tile[32][33];
  int s0 = blockIdx.x * 32;
  int d0 = blockIdx.y * 32;
  int g  = blockIdx.z;
  int t = threadIdx.x;
  int r = t >> 5, c = t & 31;
#pragma unroll
  for (int p = 0; p < 4; ++p)
    tile[r + p * 8][c] = QKV[(size_t)(s0 + r + p * 8) * QKVN + 5120 + g * 128 + d0 + c];
  __syncthreads();
#pragma unroll
  for (int p = 0; p < 4; ++p)
    Vt_g[(size_t)(g * 128 + d0 + r + p * 8) * SEQ + s0 + c] = tile[c][r + p * 8];
}

// ---------------- 128x128 GEMM, BK=64, swizzled LDS (proven r5-r8; restored) ----------------
template <typename OUT_T>
__global__ __launch_bounds__(256) void gemm_bt(const bf16* __restrict__ A,
                                               const bf16* __restrict__ Bt,
                                               OUT_T* __restrict__ C,
                                               int K, int ldc) {
  __shared__ __align__(16) bf16 Abuf[128 * 64];
  __shared__ __align__(16) bf16 Bbuf[128 * 64];
  int m0 = blockIdx.y * 128, n0 = blockIdx.x * 128;
  int tid = threadIdx.x, w = tid >> 6, lane = tid & 63;
  int wr = w >> 1, wc = w & 1;
  int l15 = lane & 15, l4 = lane >> 4;
  f32x4 acc[4][4] = {};
  const int nk = K >> 6;
  for (int kt = 0; kt < nk; ++kt) {
    int k0 = kt << 6;
#pragma unroll
    for (int p = 0; p < 4; ++p) {
      int c = p * 256 + tid;
      int row = c >> 3, slot = c & 7;
      int ssl = (slot ^ (row & 7)) << 4;
      gload_lds16((const char*)(A + (size_t)(m0 + row) * K + k0) + ssl, (char*)Abuf + c * 16);
      gload_lds16((const char*)(Bt + (size_t)(n0 + row) * K + k0) + ssl, (char*)Bbuf + c * 16);
    }
    __syncthreads();
    bf16x8 af[4][2], bfr[4][2];
#pragma unroll
    for (int m = 0; m < 4; ++m)
#pragma unroll
      for (int kk = 0; kk < 2; ++kk) {
        int row = wr * 64 + m * 16 + l15;
        af[m][kk] = *(const bf16x8*)((const char*)Abuf + row * 128 +
                                     (((kk * 4 + l4) ^ (row & 7)) << 4));
      }
#pragma unroll
    for (int n = 0; n < 4; ++n)
#pragma unroll
      for (int kk = 0; kk < 2; ++kk) {
        int row = wc * 64 + n * 16 + l15;
        bfr[n][kk] = *(const bf16x8*)((const char*)Bbuf + row * 128 +
                                      (((kk * 4 + l4) ^ (row & 7)) << 4));
      }
#pragma unroll
    for (int kk = 0; kk < 2; ++kk)
#pragma unroll
      for (int m = 0; m < 4; ++m)
#pragma unroll
        for (int n = 0; n < 4; ++n)
          acc[m][n] = __builtin_amdgcn_mfma_f32_16x16x32_bf16(af[m][kk], bfr[n][kk],
                                                              acc[m][n], 0, 0, 0);
    __syncthreads();
  }
#pragma unroll
  for (int m = 0; m < 4; ++m)
#pragma unroll
    for (int n = 0; n < 4; ++n)
#pragma unroll
      for (int i = 0; i < 4; ++i) {
        int row = m0 + wr * 64 + m * 16 + l4 * 4 + i;
        int col = n0 + wc * 64 + n * 16 + l15;
        C[(size_t)row * ldc + col] = (OUT_T)acc[m][n][i];
      }
}

// ---------------- attention v7: v6 + V direct from XCD-L2 (no V staging) ----------------
// 512 blocks x 256 thr (4 waves), g = bid&7 pins each kv-head's K/V to one XCD's L2
// (Vt_g per head = 1MB << 4MB L2). V-frags read straight from Vt_g at the verified
// coordinates (d = dt*32+l31, k = kb+kstep*16+hh*8) — the LDS-V slot formula collapses
// to this (derived r8, HW-verified). K staged in LDS (dbuf 32KB); stage traffic halved.
// PV V-loads software-pipelined: dt=0 group issued BEFORE softmax (VALU hides L2 latency),
// dt+1 group issued before dt's MFMAs. 3 blocks/CU (launch_bounds(256,3), LDS 96KB/CU).
__global__ __launch_bounds__(256, 3) void attn_kernel(const bf16* __restrict__ QKV,
                                                      const bf16* __restrict__ Vt_g,
                                                      bf16* __restrict__ attn) {
  __shared__ __align__(16) bf16 Klds[2][64 * 128];
  const int bid = blockIdx.x;
  const int g = bid & 7;
  const int rest = bid >> 3;
  const int hi = rest & 3;
  const int pair = rest >> 2;            // 0..15
  const int qb_a = pair, qb_b = 31 - pair;
  const int tid = threadIdx.x, w = tid >> 6, lane = tid & 63;
  const int l31 = lane & 31, hh = lane >> 5;
  const int head = g * 4 + hi;
  const bool isB = (w < 2);
  const int myqb = isB ? qb_b : qb_a;
  const int unit_q0 = myqb * 64 + (w & 1) * 32;
  const int qcol = head * 128;
  const int kcol = 4096 + g * 128;
  const float scale = 0.08838834764831845f;  // 1/sqrt(128)
  const float LOG2E = 1.4426950408889634f;

  const bf16* Vhead = Vt_g + (size_t)g * 128 * SEQ;
  // per-lane V row base: row = dt*32 + l31 (dt offset added per-iteration)
  const bf16* vlane = Vhead + (size_t)l31 * SEQ + hh * 8;

  bf16x8 qf[8];
#pragma unroll
  for (int db = 0; db < 8; ++db)
    qf[db] = *(const bf16x8*)(QKV + (size_t)(unit_q0 + l31) * QKVN + qcol +
                              db * 16 + hh * 8);

  f32x16 acc_o[4] = {};
  float m_run = -1e30f, l_run = 0.f;

  // stage K tile only (1024 16B-chunks, 256 thr x 4)
  auto stageK = [&](int kb, int buf) {
#pragma unroll
    for (int j = 0; j < 4; ++j) {
      int c = tid + (j << 8);
      int row = c >> 4, s = c & 15;
      int sl = s ^ (row & 15);
      gload_lds16((const char*)(QKV + (size_t)(kb + row) * QKVN + kcol) + (sl << 4),
                  (char*)Klds[buf] + (c << 4));
    }
  };

  auto compute_unit = [&](int kb, int cur) {
    const char* Kb = (const char*)Klds[cur];
    f32x16 s0 = {}, s1 = {};
    __builtin_amdgcn_s_setprio(1);
#pragma unroll
    for (int db = 0; db < 8; ++db) {
      int slot = (db * 2 + hh) ^ (l31 & 15);
      bf16x8 k0 = *(const bf16x8*)(Kb + l31 * 256 + slot * 16);
      bf16x8 k1 = *(const bf16x8*)(Kb + (32 + l31) * 256 + slot * 16);
      s0 = __builtin_amdgcn_mfma_f32_32x32x16_bf16(k0, qf[db], s0, 0, 0, 0);
      s1 = __builtin_amdgcn_mfma_f32_32x32x16_bf16(k1, qf[db], s1, 0, 0, 0);
    }
    __builtin_amdgcn_s_setprio(0);
    // ---- issue dt=0 V-loads now; softmax VALU below hides their L2 latency ----
    const bf16* vb0 = vlane + kb;
    bf16x8 vc[4];
#pragma unroll
    for (int ks = 0; ks < 4; ++ks)
      vc[ks] = *(const bf16x8*)(vb0 + ks * 16);
    // ---- scale + causal mask ----
    float p0[16], p1[16];
    const bool needmask = (kb + 64 > unit_q0);
    const int qg = unit_q0 + l31;
#pragma unroll
    for (int r = 0; r < 16; ++r) {
      float v0 = s0[r] * scale, v1 = s1[r] * scale;
      if (needmask) {
        int krow = (r & 3) + 8 * (r >> 2) + 4 * hh;
        if (kb + krow > qg)      v0 = -1e30f;
        if (kb + 32 + krow > qg) v1 = -1e30f;
      }
      p0[r] = v0; p1[r] = v1;
    }
    float t = fmaxf(p0[0], p1[0]);
#pragma unroll
    for (int r = 1; r < 16; ++r) t = fmaxf(t, fmaxf(p0[r], p1[r]));
    t = fmaxf(t, __shfl_xor(t, 32));
    if (!__all(t - m_run <= 8.0f)) {     // T13 defer-max
      float mnew = fmaxf(m_run, t);
      float fac = exp2f((m_run - mnew) * LOG2E);
      m_run = mnew;
      l_run *= fac;
#pragma unroll
      for (int dt = 0; dt < 4; ++dt)
#pragma unroll
        for (int r = 0; r < 16; ++r) acc_o[dt][r] *= fac;
    }
    float psum = 0.f;
#pragma unroll
    for (int r = 0; r < 16; ++r) {
      p0[r] = exp2f((p0[r] - m_run) * LOG2E); psum += p0[r];
      p1[r] = exp2f((p1[r] - m_run) * LOG2E); psum += p1[r];
    }
    psum += __shfl_xor(psum, 32);
    l_run += psum;
    // ---- P -> bf16 b-frags in-register (T12, verified r8) ----
    bf16x8 paf[4];
#pragma unroll
    for (int kstep = 0; kstep < 4; ++kstep) {
      const float* p = (kstep < 2) ? p0 : p1;
      const int base = (kstep & 1) * 8;
      unsigned a0 = cvtpk(p[base + 0], p[base + 1]);
      unsigned b0 = cvtpk(p[base + 4], p[base + 5]);
      plswap(a0, b0);
      unsigned a1 = cvtpk(p[base + 2], p[base + 3]);
      unsigned b1 = cvtpk(p[base + 6], p[base + 7]);
      plswap(a1, b1);
      u32x4 pw; pw[0] = a0; pw[1] = a1; pw[2] = b0; pw[3] = b1;
      paf[kstep] = __builtin_bit_cast(bf16x8, pw);
    }
    // ---- PV: V from L2, double-buffered across dt ----
    __builtin_amdgcn_s_setprio(1);
#pragma unroll
    for (int dt = 0; dt < 4; ++dt) {
      bf16x8 vn[4];
      if (dt < 3) {
        const bf16* nb = vb0 + (size_t)(dt + 1) * 32 * SEQ;
#pragma unroll
        for (int ks = 0; ks < 4; ++ks)
          vn[ks] = *(const bf16x8*)(nb + ks * 16);
      }
#pragma unroll
      for (int ks = 0; ks < 4; ++ks)
        acc_o[dt] = __builtin_amdgcn_mfma_f32_32x32x16_bf16(vc[ks], paf[ks], acc_o[dt], 0, 0, 0);
#pragma unroll
      for (int ks = 0; ks < 4; ++ks) vc[ks] = vn[ks];
    }
    __builtin_amdgcn_s_setprio(0);
  };

  stageK(0, 0);
  __syncthreads();

  int cur = 0;
  for (int kbi = 0; kbi <= qb_b; ++kbi) {
    int kb = kbi * 64;
    if (kbi < qb_b) stageK(kb + 64, cur ^ 1);   // issue-early, overlaps compute
    if (isB || kbi <= qb_a) compute_unit(kb, cur);
    __syncthreads();
    cur ^= 1;
  }

  float inv_l = 1.0f / l_run;
  bf16* orow = attn + (size_t)(unit_q0 + l31) * 4096 + qcol;
#pragma unroll
  for (int dt = 0; dt < 4; ++dt)
#pragma unroll
    for (int r = 0; r < 16; ++r) {
      int d = dt * 32 + (r & 3) + 8 * (r >> 2) + 4 * hh;
      orow[d] = (bf16)(acc_o[dt][r] * inv_l);
    }
}

extern "C" void kernel_launch(void* const* d_in, const int* in_sizes, int n_in,
                              void* d_out, int out_size, void* d_ws, size_t ws_size,
                              hipStream_t stream) {
  const float* X  = (const float*)d_in[0];
  const float* Wq = (const float*)d_in[1];
  const float* Wk = (const float*)d_in[2];
  const float* Wv = (const float*)d_in[3];
  const float* Wo = (const float*)d_in[4];
  float* out = (float*)d_out;

  const size_t XB_OFF  = 0;
  const size_t WT_OFF  = 16777216;
  const size_t VT_OFF  = WT_OFF + 33554432;       // inside Wt region, past Wo^T
  const size_t QKV_OFF = 16777216 + 50331648;
  if (ws_size < (size_t)92274688) return;

  char* ws = (char*)d_ws;
  bf16* Xb    = (bf16*)(ws + XB_OFF);
  bf16* Wt    = (bf16*)(ws + WT_OFF);
  bf16* Vt_g  = (bf16*)(ws + VT_OFF);
  bf16* QKV   = (bf16*)(ws + QKV_OFF);
  bf16* attnb = Xb;  // reuse after gemm1 consumed Xb

  // 1. cast hidden states
  cast_f32_bf16<<<2048, 256, 0, stream>>>(X, Xb, SEQ * HID);
  // 2. transpose-cast Wq/Wk/Wv into fused [6144][4096] B^T
  transpose_cast<<<dim3(4096 / 64, 4096 / 64), 256, 0, stream>>>(Wq, Wt, 4096, 0);
  transpose_cast<<<dim3(1024 / 64, 4096 / 64), 256, 0, stream>>>(Wk, Wt, 1024, 4096);
  transpose_cast<<<dim3(1024 / 64, 4096 / 64), 256, 0, stream>>>(Wv, Wt, 1024, 5120);
  // 3. fused QKV projection: [2048,4096] @ [4096,6144]
  gemm_bt<bf16><<<dim3(QKVN / 128, SEQ / 128), 256, 0, stream>>>(Xb, Wt, QKV, HID, QKVN);
  // 4. transpose-cast Wo (reuses Wt space) + transpose V into global [g][d][s]
  transpose_cast<<<dim3(4096 / 64, 4096 / 64), 256, 0, stream>>>(Wo, Wt, 4096, 0);
  transpose_v<<<dim3(SEQ / 32, 4, 8), 256, 0, stream>>>(QKV, Vt_g);
  // 5. causal GQA flash attention v7 (V direct from XCD-L2, K staged, 3 blocks/CU)
  attn_kernel<<<512, 256, 0, stream>>>(QKV, Vt_g, attnb);
  // 6. output projection -> f32 out: [2048,4096] @ [4096,4096]
  gemm_bt<float><<<dim3(4096 / 128, SEQ / 128), 256, 0, stream>>>(attnb, Wt, out, HID, 4096);
}

// Round 12
// 366.262 us; speedup vs baseline: 1.4271x; 1.4271x over previous
//
#include <hip/hip_runtime.h>
#include <hip/hip_bf16.h>

typedef __bf16 bf16;
typedef __bf16 bf16x4 __attribute__((ext_vector_type(4)));
typedef __bf16 bf16x8 __attribute__((ext_vector_type(8)));
typedef float  f32x4  __attribute__((ext_vector_type(4)));
typedef float  f32x16 __attribute__((ext_vector_type(16)));
typedef unsigned u32x4 __attribute__((ext_vector_type(4)));

#define SEQ  2048
#define HID  4096
#define QKVN 6144   // 4096 Q + 1024 K + 1024 V

__device__ __forceinline__ void gload_lds16(const void* g, void* l) {
  __builtin_amdgcn_global_load_lds(
      (const __attribute__((address_space(1))) void*)g,
      (__attribute__((address_space(3))) void*)l, 16, 0, 0);
}

// v_cvt_pk_bf16_f32: lo -> D[15:0], hi -> D[31:16] (RNE; no builtin on gfx950)
__device__ __forceinline__ unsigned cvtpk(float lo, float hi) {
  unsigned r;
  asm("v_cvt_pk_bf16_f32 %0, %1, %2" : "=v"(r) : "v"(lo), "v"(hi));
  return r;
}
__device__ __forceinline__ void plswap(unsigned& a, unsigned& b) {
  asm("v_permlane32_swap_b32 %0, %1" : "+v"(a), "+v"(b));
}

// ---------------- cast f32 -> bf16 (vectorized) ----------------
__global__ __launch_bounds__(256) void cast_f32_bf16(const float* __restrict__ in,
                                                     bf16* __restrict__ out, int n) {
  int i = (blockIdx.x * 256 + threadIdx.x) * 4;
  int stride = gridDim.x * 256 * 4;
  for (; i < n; i += stride) {
    float4 v = *(const float4*)(in + i);
    bf16x4 o;
    o[0] = (bf16)v.x; o[1] = (bf16)v.y; o[2] = (bf16)v.z; o[3] = (bf16)v.w;
    *(bf16x4*)(out + i) = o;
  }
}

// ---------------- tiled transpose + cast: W[4096][N] f32 -> Wt[roff+N][4096] bf16 ----------------
__global__ __launch_bounds__(256) void transpose_cast(const float* __restrict__ W,
                                                      bf16* __restrict__ Wt,
                                                      int N, int roff) {
  __shared__ float tile[64][65];
  int k0 = blockIdx.y * 64;
  int n0 = blockIdx.x * 64;
  int t = threadIdx.x;
  int lr = t >> 4;            // 0..15
  int lc = (t & 15) * 4;      // 0,4,...,60
#pragma unroll
  for (int p = 0; p < 4; ++p) {
    int row = p * 16 + lr;
    float4 v = *(const float4*)(W + (size_t)(k0 + row) * N + n0 + lc);
    tile[row][lc] = v.x; tile[row][lc + 1] = v.y;
    tile[row][lc + 2] = v.z; tile[row][lc + 3] = v.w;
  }
  __syncthreads();
#pragma unroll
  for (int p = 0; p < 4; ++p) {
    int n = p * 16 + lr;
    bf16x4 o;
#pragma unroll
    for (int q = 0; q < 4; ++q) o[q] = (bf16)tile[lc + q][n];
    *(bf16x4*)(Wt + (size_t)(roff + n0 + n) * 4096 + k0 + lc) = o;
  }
}

// ---------------- transpose V out of QKV into global: Vt_g[g][d][s] ----------------
__global__ __launch_bounds__(256) void transpose_v(const bf16* __restrict__ QKV,
                                                   bf16* __restrict__ Vt_g) {
  __shared__ bf16 tile[32][33];
  int s0 = blockIdx.x * 32;
  int d0 = blockIdx.y * 32;
  int g  = blockIdx.z;
  int t = threadIdx.x;
  int r = t >> 5, c = t & 31;
#pragma unroll
  for (int p = 0; p < 4; ++p)
    tile[r + p * 8][c] = QKV[(size_t)(s0 + r + p * 8) * QKVN + 5120 + g * 128 + d0 + c];
  __syncthreads();
#pragma unroll
  for (int p = 0; p < 4; ++p)
    Vt_g[(size_t)(g * 128 + d0 + r + p * 8) * SEQ + s0 + c] = tile[c][r + p * 8];
}

// ---------------- 128x128 GEMM, BK=64, swizzled LDS (proven r5-r8) ----------------
template <typename OUT_T>
__global__ __launch_bounds__(256) void gemm_bt(const bf16* __restrict__ A,
                                               const bf16* __restrict__ Bt,
                                               OUT_T* __restrict__ C,
                                               int K, int ldc) {
  __shared__ __align__(16) bf16 Abuf[128 * 64];
  __shared__ __align__(16) bf16 Bbuf[128 * 64];
  int m0 = blockIdx.y * 128, n0 = blockIdx.x * 128;
  int tid = threadIdx.x, w = tid >> 6, lane = tid & 63;
  int wr = w >> 1, wc = w & 1;
  int l15 = lane & 15, l4 = lane >> 4;
  f32x4 acc[4][4] = {};
  const int nk = K >> 6;
  for (int kt = 0; kt < nk; ++kt) {
    int k0 = kt << 6;
#pragma unroll
    for (int p = 0; p < 4; ++p) {
      int c = p * 256 + tid;
      int row = c >> 3, slot = c & 7;
      int ssl = (slot ^ (row & 7)) << 4;
      gload_lds16((const char*)(A + (size_t)(m0 + row) * K + k0) + ssl, (char*)Abuf + c * 16);
      gload_lds16((const char*)(Bt + (size_t)(n0 + row) * K + k0) + ssl, (char*)Bbuf + c * 16);
    }
    __syncthreads();
    bf16x8 af[4][2], bfr[4][2];
#pragma unroll
    for (int m = 0; m < 4; ++m)
#pragma unroll
      for (int kk = 0; kk < 2; ++kk) {
        int row = wr * 64 + m * 16 + l15;
        af[m][kk] = *(const bf16x8*)((const char*)Abuf + row * 128 +
                                     (((kk * 4 + l4) ^ (row & 7)) << 4));
      }
#pragma unroll
    for (int n = 0; n < 4; ++n)
#pragma unroll
      for (int kk = 0; kk < 2; ++kk) {
        int row = wc * 64 + n * 16 + l15;
        bfr[n][kk] = *(const bf16x8*)((const char*)Bbuf + row * 128 +
                                      (((kk * 4 + l4) ^ (row & 7)) << 4));
      }
#pragma unroll
    for (int kk = 0; kk < 2; ++kk)
#pragma unroll
      for (int m = 0; m < 4; ++m)
#pragma unroll
        for (int n = 0; n < 4; ++n)
          acc[m][n] = __builtin_amdgcn_mfma_f32_16x16x32_bf16(af[m][kk], bfr[n][kk],
                                                              acc[m][n], 0, 0, 0);
    __syncthreads();
  }
#pragma unroll
  for (int m = 0; m < 4; ++m)
#pragma unroll
    for (int n = 0; n < 4; ++n)
#pragma unroll
      for (int i = 0; i < 4; ++i) {
        int row = m0 + wr * 64 + m * 16 + l4 * 4 + i;
        int col = n0 + wc * 64 + n * 16 + l15;
        C[(size_t)row * ldc + col] = (OUT_T)acc[m][n][i];
      }
}

// ---------------- attention v6.1: r8's proven v6 + complementary-pair CU balance ----------------
// 512 blocks x 256 thr (4 waves). g = bid&7 -> XCD. pr = bid>>5 (0..15); pair remapped
// pr<8 ? pr : 23-pr so co-resident blocks (c, c+256 under round-robin) get pairs (p, 15-p):
// per-CU work = (32-p)+(17+p) = 49 tile-times, constant (was 42..56, 14% makespan slack).
// Waves 0,1 = q-block qb_b halves (always active); waves 2,3 = qb_a (guarded).
// Swapped QK^T (mfma(K,Q)), in-register softmax, T12 cvt_pk+permlane, T13 defer-max.
__global__ __launch_bounds__(256, 2) void attn_kernel(const bf16* __restrict__ QKV,
                                                      const bf16* __restrict__ Vt_g,
                                                      bf16* __restrict__ attn) {
  __shared__ __align__(16) bf16 Klds[2][64 * 128];
  __shared__ __align__(16) bf16 Vlds[2][64 * 128];
  const int bid = blockIdx.x;
  const int g = bid & 7;
  const int rest = bid >> 3;
  const int hi = rest & 3;
  const int pr = rest >> 2;              // 0..15
  const int pair = (pr < 8) ? pr : (23 - pr);   // complementary-pair remap
  const int qb_a = pair, qb_b = 31 - pair;
  const int tid = threadIdx.x, w = tid >> 6, lane = tid & 63;
  const int l31 = lane & 31, hh = lane >> 5;
  const int head = g * 4 + hi;
  const bool isB = (w < 2);
  const int myqb = isB ? qb_b : qb_a;
  const int unit_q0 = myqb * 64 + (w & 1) * 32;
  const int qcol = head * 128;
  const int kcol = 4096 + g * 128;
  const float scale = 0.08838834764831845f;  // 1/sqrt(128)
  const float LOG2E = 1.4426950408889634f;

  const bf16* Vhead = Vt_g + (size_t)g * 128 * SEQ;

  bf16x8 qf[8];
#pragma unroll
  for (int db = 0; db < 8; ++db)
    qf[db] = *(const bf16x8*)(QKV + (size_t)(unit_q0 + l31) * QKVN + qcol +
                              db * 16 + hh * 8);

  f32x16 acc_o[4] = {};
  float m_run = -1e30f, l_run = 0.f;

  auto stageKV = [&](int kb, int buf) {
#pragma unroll
    for (int j = 0; j < 4; ++j) {
      int c = tid + (j << 8);
      int row = c >> 4, s = c & 15;
      int sl = s ^ (row & 15);
      gload_lds16((const char*)(QKV + (size_t)(kb + row) * QKVN + kcol) + (sl << 4),
                  (char*)Klds[buf] + (c << 4));
      int d = row * 2 + (sl >> 3);
      int ko = (sl & 7) << 3;
      gload_lds16(Vhead + (size_t)d * SEQ + kb + ko, (char*)Vlds[buf] + (c << 4));
    }
  };

  auto compute_unit = [&](int kb, int cur) {
    const char* Kb = (const char*)Klds[cur];
    const char* Vb = (const char*)Vlds[cur];
    f32x16 s0 = {}, s1 = {};
    __builtin_amdgcn_s_setprio(1);
#pragma unroll
    for (int db = 0; db < 8; ++db) {
      int slot = (db * 2 + hh) ^ (l31 & 15);
      bf16x8 k0 = *(const bf16x8*)(Kb + l31 * 256 + slot * 16);
      bf16x8 k1 = *(const bf16x8*)(Kb + (32 + l31) * 256 + slot * 16);
      s0 = __builtin_amdgcn_mfma_f32_32x32x16_bf16(k0, qf[db], s0, 0, 0, 0);
      s1 = __builtin_amdgcn_mfma_f32_32x32x16_bf16(k1, qf[db], s1, 0, 0, 0);
    }
    __builtin_amdgcn_s_setprio(0);
    float p0[16], p1[16];
    const bool needmask = (kb + 64 > unit_q0);
    const int qg = unit_q0 + l31;
#pragma unroll
    for (int r = 0; r < 16; ++r) {
      float v0 = s0[r] * scale, v1 = s1[r] * scale;
      if (needmask) {
        int krow = (r & 3) + 8 * (r >> 2) + 4 * hh;
        if (kb + krow > qg)      v0 = -1e30f;
        if (kb + 32 + krow > qg) v1 = -1e30f;
      }
      p0[r] = v0; p1[r] = v1;
    }
    float t = fmaxf(p0[0], p1[0]);
#pragma unroll
    for (int r = 1; r < 16; ++r) t = fmaxf(t, fmaxf(p0[r], p1[r]));
    t = fmaxf(t, __shfl_xor(t, 32));
    if (!__all(t - m_run <= 8.0f)) {     // T13 defer-max
      float mnew = fmaxf(m_run, t);
      float fac = exp2f((m_run - mnew) * LOG2E);
      m_run = mnew;
      l_run *= fac;
#pragma unroll
      for (int dt = 0; dt < 4; ++dt)
#pragma unroll
        for (int r = 0; r < 16; ++r) acc_o[dt][r] *= fac;
    }
    float psum = 0.f;
#pragma unroll
    for (int r = 0; r < 16; ++r) {
      p0[r] = exp2f((p0[r] - m_run) * LOG2E); psum += p0[r];
      p1[r] = exp2f((p1[r] - m_run) * LOG2E); psum += p1[r];
    }
    psum += __shfl_xor(psum, 32);
    l_run += psum;
    bf16x8 paf[4];
#pragma unroll
    for (int kstep = 0; kstep < 4; ++kstep) {
      const float* p = (kstep < 2) ? p0 : p1;
      const int base = (kstep & 1) * 8;
      unsigned a0 = cvtpk(p[base + 0], p[base + 1]);
      unsigned b0 = cvtpk(p[base + 4], p[base + 5]);
      plswap(a0, b0);
      unsigned a1 = cvtpk(p[base + 2], p[base + 3]);
      unsigned b1 = cvtpk(p[base + 6], p[base + 7]);
      plswap(a1, b1);
      u32x4 pw; pw[0] = a0; pw[1] = a1; pw[2] = b0; pw[3] = b1;
      paf[kstep] = __builtin_bit_cast(bf16x8, pw);
    }
    __builtin_amdgcn_s_setprio(1);
#pragma unroll
    for (int dt = 0; dt < 4; ++dt) {
      int vrow = dt * 16 + (l31 >> 1);
#pragma unroll
      for (int kstep = 0; kstep < 4; ++kstep) {
        int slot = ((l31 & 1) * 8 + kstep * 2 + hh) ^ (vrow & 15);
        bf16x8 vf = *(const bf16x8*)(Vb + vrow * 256 + slot * 16);
        acc_o[dt] = __builtin_amdgcn_mfma_f32_32x32x16_bf16(vf, paf[kstep], acc_o[dt], 0, 0, 0);
      }
    }
    __builtin_amdgcn_s_setprio(0);
  };

  stageKV(0, 0);
  __syncthreads();

  int cur = 0;
  for (int kbi = 0; kbi <= qb_b; ++kbi) {
    int kb = kbi * 64;
    if (kbi < qb_b) stageKV(kb + 64, cur ^ 1);
    if (isB || kbi <= qb_a) compute_unit(kb, cur);
    __syncthreads();
    cur ^= 1;
  }

  float inv_l = 1.0f / l_run;
  bf16* orow = attn + (size_t)(unit_q0 + l31) * 4096 + qcol;
#pragma unroll
  for (int dt = 0; dt < 4; ++dt)
#pragma unroll
    for (int r = 0; r < 16; ++r) {
      int d = dt * 32 + (r & 3) + 8 * (r >> 2) + 4 * hh;
      orow[d] = (bf16)(acc_o[dt][r] * inv_l);
    }
}

extern "C" void kernel_launch(void* const* d_in, const int* in_sizes, int n_in,
                              void* d_out, int out_size, void* d_ws, size_t ws_size,
                              hipStream_t stream) {
  const float* X  = (const float*)d_in[0];
  const float* Wq = (const float*)d_in[1];
  const float* Wk = (const float*)d_in[2];
  const float* Wv = (const float*)d_in[3];
  const float* Wo = (const float*)d_in[4];
  float* out = (float*)d_out;

  const size_t XB_OFF  = 0;
  const size_t WT_OFF  = 16777216;
  const size_t VT_OFF  = WT_OFF + 33554432;       // inside Wt region, past Wo^T
  const size_t QKV_OFF = 16777216 + 50331648;
  if (ws_size < (size_t)92274688) return;

  char* ws = (char*)d_ws;
  bf16* Xb    = (bf16*)(ws + XB_OFF);
  bf16* Wt    = (bf16*)(ws + WT_OFF);
  bf16* Vt_g  = (bf16*)(ws + VT_OFF);
  bf16* QKV   = (bf16*)(ws + QKV_OFF);
  bf16* attnb = Xb;  // reuse after gemm1 consumed Xb

  // 1. cast hidden states
  cast_f32_bf16<<<2048, 256, 0, stream>>>(X, Xb, SEQ * HID);
  // 2. transpose-cast Wq/Wk/Wv into fused [6144][4096] B^T
  transpose_cast<<<dim3(4096 / 64, 4096 / 64), 256, 0, stream>>>(Wq, Wt, 4096, 0);
  transpose_cast<<<dim3(1024 / 64, 4096 / 64), 256, 0, stream>>>(Wk, Wt, 1024, 4096);
  transpose_cast<<<dim3(1024 / 64, 4096 / 64), 256, 0, stream>>>(Wv, Wt, 1024, 5120);
  // 3. fused QKV projection: [2048,4096] @ [4096,6144]
  gemm_bt<bf16><<<dim3(QKVN / 128, SEQ / 128), 256, 0, stream>>>(Xb, Wt, QKV, HID, QKVN);
  // 4. transpose-cast Wo (reuses Wt space) + transpose V into global [g][d][s]
  transpose_cast<<<dim3(4096 / 64, 4096 / 64), 256, 0, stream>>>(Wo, Wt, 4096, 0);
  transpose_v<<<dim3(SEQ / 32, 4, 8), 256, 0, stream>>>(QKV, Vt_g);
  // 5. causal GQA flash attention v6.1 (complementary-pair CU balance)
  attn_kernel<<<512, 256, 0, stream>>>(QKV, Vt_g, attnb);
  // 6. output projection -> f32 out: [2048,4096] @ [4096,4096]
  gemm_bt<float><<<dim3(4096 / 128, SEQ / 128), 256, 0, stream>>>(attnb, Wt, out, HID, 4096);
}

// Round 13
// 364.891 us; speedup vs baseline: 1.4324x; 1.0038x over previous
//
#include <hip/hip_runtime.h>
#include <hip/hip_bf16.h>

typedef __bf16 bf16;
typedef __bf16 bf16x4 __attribute__((ext_vector_type(4)));
typedef __bf16 bf16x8 __attribute__((ext_vector_type(8)));
typedef float  f32x4  __attribute__((ext_vector_type(4)));
typedef float  f32x16 __attribute__((ext_vector_type(16)));
typedef unsigned u32x4 __attribute__((ext_vector_type(4)));

#define SEQ  2048
#define HID  4096
#define QKVN 6144   // 4096 Q + 1024 K + 1024 V

__device__ __forceinline__ void gload_lds16(const void* g, void* l) {
  __builtin_amdgcn_global_load_lds(
      (const __attribute__((address_space(1))) void*)g,
      (__attribute__((address_space(3))) void*)l, 16, 0, 0);
}

// v_cvt_pk_bf16_f32: lo -> D[15:0], hi -> D[31:16] (RNE; no builtin on gfx950)
__device__ __forceinline__ unsigned cvtpk(float lo, float hi) {
  unsigned r;
  asm("v_cvt_pk_bf16_f32 %0, %1, %2" : "=v"(r) : "v"(lo), "v"(hi));
  return r;
}
__device__ __forceinline__ void plswap(unsigned& a, unsigned& b) {
  asm("v_permlane32_swap_b32 %0, %1" : "+v"(a), "+v"(b));
}
// raw v_exp_f32 (= exp2). Valid here: inputs always <= 0, finite or ~-1e30 (exp->0).
// Skips OCML's range/denormal guard that exp2f drags in.
__device__ __forceinline__ float vexp2(float x) {
  float r;
  asm("v_exp_f32 %0, %1" : "=v"(r) : "v"(x));
  return r;
}

// ---------------- cast f32 -> bf16 (vectorized) ----------------
__global__ __launch_bounds__(256) void cast_f32_bf16(const float* __restrict__ in,
                                                     bf16* __restrict__ out, int n) {
  int i = (blockIdx.x * 256 + threadIdx.x) * 4;
  int stride = gridDim.x * 256 * 4;
  for (; i < n; i += stride) {
    float4 v = *(const float4*)(in + i);
    bf16x4 o;
    o[0] = (bf16)v.x; o[1] = (bf16)v.y; o[2] = (bf16)v.z; o[3] = (bf16)v.w;
    *(bf16x4*)(out + i) = o;
  }
}

// ---------------- merged Wq/Wk/Wv transpose-cast: one launch -> Wt[6144][4096] bf16 ----------
// gy = output-row block over [0,6144): [0,4096)=Wq, [4096,5120)=Wk, [5120,6144)=Wv.
// Body identical to the proven 64x64 vectorized transpose (float4 loads, bf16x4 stores,
// [64][65] pad = 2-way bank aliasing, free).
__global__ __launch_bounds__(256) void transpose_wqkv(const float* __restrict__ Wq,
                                                      const float* __restrict__ Wk,
                                                      const float* __restrict__ Wv,
                                                      bf16* __restrict__ Wt) {
  __shared__ float tile[64][65];
  int k0 = blockIdx.x * 64;
  int gy = blockIdx.y;               // 0..95
  int orow = gy * 64;                // output row base
  const float* W; int N, n0;
  if (orow < 4096)      { W = Wq; N = 4096; n0 = orow; }
  else if (orow < 5120) { W = Wk; N = 1024; n0 = orow - 4096; }
  else                  { W = Wv; N = 1024; n0 = orow - 5120; }
  int t = threadIdx.x;
  int lr = t >> 4;            // 0..15
  int lc = (t & 15) * 4;      // 0,4,...,60
#pragma unroll
  for (int p = 0; p < 4; ++p) {
    int row = p * 16 + lr;
    float4 v = *(const float4*)(W + (size_t)(k0 + row) * N + n0 + lc);
    tile[row][lc] = v.x; tile[row][lc + 1] = v.y;
    tile[row][lc + 2] = v.z; tile[row][lc + 3] = v.w;
  }
  __syncthreads();
#pragma unroll
  for (int p = 0; p < 4; ++p) {
    int n = p * 16 + lr;
    bf16x4 o;
#pragma unroll
    for (int q = 0; q < 4; ++q) o[q] = (bf16)tile[lc + q][n];
    *(bf16x4*)(Wt + (size_t)(orow + n) * 4096 + k0 + lc) = o;
  }
}

// ---------------- single transpose + cast (Wo): W[4096][4096] f32 -> Wt[4096][4096] bf16 ----
__global__ __launch_bounds__(256) void transpose_cast(const float* __restrict__ W,
                                                      bf16* __restrict__ Wt,
                                                      int N, int roff) {
  __shared__ float tile[64][65];
  int k0 = blockIdx.y * 64;
  int n0 = blockIdx.x * 64;
  int t = threadIdx.x;
  int lr = t >> 4;
  int lc = (t & 15) * 4;
#pragma unroll
  for (int p = 0; p < 4; ++p) {
    int row = p * 16 + lr;
    float4 v = *(const float4*)(W + (size_t)(k0 + row) * N + n0 + lc);
    tile[row][lc] = v.x; tile[row][lc + 1] = v.y;
    tile[row][lc + 2] = v.z; tile[row][lc + 3] = v.w;
  }
  __syncthreads();
#pragma unroll
  for (int p = 0; p < 4; ++p) {
    int n = p * 16 + lr;
    bf16x4 o;
#pragma unroll
    for (int q = 0; q < 4; ++q) o[q] = (bf16)tile[lc + q][n];
    *(bf16x4*)(Wt + (size_t)(roff + n0 + n) * 4096 + k0 + lc) = o;
  }
}

// ---------------- transpose V out of QKV into global: Vt_g[g][d][s] ----------------
__global__ __launch_bounds__(256) void transpose_v(const bf16* __restrict__ QKV,
                                                   bf16* __restrict__ Vt_g) {
  __shared__ bf16 tile[32][33];
  int s0 = blockIdx.x * 32;
  int d0 = blockIdx.y * 32;
  int g  = blockIdx.z;
  int t = threadIdx.x;
  int r = t >> 5, c = t & 31;
#pragma unroll
  for (int p = 0; p < 4; ++p)
    tile[r + p * 8][c] = QKV[(size_t)(s0 + r + p * 8) * QKVN + 5120 + g * 128 + d0 + c];
  __syncthreads();
#pragma unroll
  for (int p = 0; p < 4; ++p)
    Vt_g[(size_t)(g * 128 + d0 + r + p * 8) * SEQ + s0 + c] = tile[c][r + p * 8];
}

// ---------------- 128x128 GEMM, BK=64, swizzled LDS (proven r5-r12, frozen) ----------------
template <typename OUT_T>
__global__ __launch_bounds__(256) void gemm_bt(const bf16* __restrict__ A,
                                               const bf16* __restrict__ Bt,
                                               OUT_T* __restrict__ C,
                                               int K, int ldc) {
  __shared__ __align__(16) bf16 Abuf[128 * 64];
  __shared__ __align__(16) bf16 Bbuf[128 * 64];
  int m0 = blockIdx.y * 128, n0 = blockIdx.x * 128;
  int tid = threadIdx.x, w = tid >> 6, lane = tid & 63;
  int wr = w >> 1, wc = w & 1;
  int l15 = lane & 15, l4 = lane >> 4;
  f32x4 acc[4][4] = {};
  const int nk = K >> 6;
  for (int kt = 0; kt < nk; ++kt) {
    int k0 = kt << 6;
#pragma unroll
    for (int p = 0; p < 4; ++p) {
      int c = p * 256 + tid;
      int row = c >> 3, slot = c & 7;
      int ssl = (slot ^ (row & 7)) << 4;
      gload_lds16((const char*)(A + (size_t)(m0 + row) * K + k0) + ssl, (char*)Abuf + c * 16);
      gload_lds16((const char*)(Bt + (size_t)(n0 + row) * K + k0) + ssl, (char*)Bbuf + c * 16);
    }
    __syncthreads();
    bf16x8 af[4][2], bfr[4][2];
#pragma unroll
    for (int m = 0; m < 4; ++m)
#pragma unroll
      for (int kk = 0; kk < 2; ++kk) {
        int row = wr * 64 + m * 16 + l15;
        af[m][kk] = *(const bf16x8*)((const char*)Abuf + row * 128 +
                                     (((kk * 4 + l4) ^ (row & 7)) << 4));
      }
#pragma unroll
    for (int n = 0; n < 4; ++n)
#pragma unroll
      for (int kk = 0; kk < 2; ++kk) {
        int row = wc * 64 + n * 16 + l15;
        bfr[n][kk] = *(const bf16x8*)((const char*)Bbuf + row * 128 +
                                      (((kk * 4 + l4) ^ (row & 7)) << 4));
      }
#pragma unroll
    for (int kk = 0; kk < 2; ++kk)
#pragma unroll
      for (int m = 0; m < 4; ++m)
#pragma unroll
        for (int n = 0; n < 4; ++n)
          acc[m][n] = __builtin_amdgcn_mfma_f32_16x16x32_bf16(af[m][kk], bfr[n][kk],
                                                              acc[m][n], 0, 0, 0);
    __syncthreads();
  }
#pragma unroll
  for (int m = 0; m < 4; ++m)
#pragma unroll
    for (int n = 0; n < 4; ++n)
#pragma unroll
      for (int i = 0; i < 4; ++i) {
        int row = m0 + wr * 64 + m * 16 + l4 * 4 + i;
        int col = n0 + wc * 64 + n * 16 + l15;
        C[(size_t)row * ldc + col] = (OUT_T)acc[m][n][i];
      }
}

// ---------------- attention v6.2: r12's v6.1 + raw v_exp_f32 in hot softmax ----------------
__global__ __launch_bounds__(256, 2) void attn_kernel(const bf16* __restrict__ QKV,
                                                      const bf16* __restrict__ Vt_g,
                                                      bf16* __restrict__ attn) {
  __shared__ __align__(16) bf16 Klds[2][64 * 128];
  __shared__ __align__(16) bf16 Vlds[2][64 * 128];
  const int bid = blockIdx.x;
  const int g = bid & 7;
  const int rest = bid >> 3;
  const int hi = rest & 3;
  const int pr = rest >> 2;              // 0..15
  const int pair = (pr < 8) ? pr : (23 - pr);   // complementary-pair CU balance
  const int qb_a = pair, qb_b = 31 - pair;
  const int tid = threadIdx.x, w = tid >> 6, lane = tid & 63;
  const int l31 = lane & 31, hh = lane >> 5;
  const int head = g * 4 + hi;
  const bool isB = (w < 2);
  const int myqb = isB ? qb_b : qb_a;
  const int unit_q0 = myqb * 64 + (w & 1) * 32;
  const int qcol = head * 128;
  const int kcol = 4096 + g * 128;
  const float scale = 0.08838834764831845f;  // 1/sqrt(128)
  const float LOG2E = 1.4426950408889634f;

  const bf16* Vhead = Vt_g + (size_t)g * 128 * SEQ;

  bf16x8 qf[8];
#pragma unroll
  for (int db = 0; db < 8; ++db)
    qf[db] = *(const bf16x8*)(QKV + (size_t)(unit_q0 + l31) * QKVN + qcol +
                              db * 16 + hh * 8);

  f32x16 acc_o[4] = {};
  float m_run = -1e30f, l_run = 0.f;

  auto stageKV = [&](int kb, int buf) {
#pragma unroll
    for (int j = 0; j < 4; ++j) {
      int c = tid + (j << 8);
      int row = c >> 4, s = c & 15;
      int sl = s ^ (row & 15);
      gload_lds16((const char*)(QKV + (size_t)(kb + row) * QKVN + kcol) + (sl << 4),
                  (char*)Klds[buf] + (c << 4));
      int d = row * 2 + (sl >> 3);
      int ko = (sl & 7) << 3;
      gload_lds16(Vhead + (size_t)d * SEQ + kb + ko, (char*)Vlds[buf] + (c << 4));
    }
  };

  auto compute_unit = [&](int kb, int cur) {
    const char* Kb = (const char*)Klds[cur];
    const char* Vb = (const char*)Vlds[cur];
    f32x16 s0 = {}, s1 = {};
    __builtin_amdgcn_s_setprio(1);
#pragma unroll
    for (int db = 0; db < 8; ++db) {
      int slot = (db * 2 + hh) ^ (l31 & 15);
      bf16x8 k0 = *(const bf16x8*)(Kb + l31 * 256 + slot * 16);
      bf16x8 k1 = *(const bf16x8*)(Kb + (32 + l31) * 256 + slot * 16);
      s0 = __builtin_amdgcn_mfma_f32_32x32x16_bf16(k0, qf[db], s0, 0, 0, 0);
      s1 = __builtin_amdgcn_mfma_f32_32x32x16_bf16(k1, qf[db], s1, 0, 0, 0);
    }
    __builtin_amdgcn_s_setprio(0);
    float p0[16], p1[16];
    const bool needmask = (kb + 64 > unit_q0);
    const int qg = unit_q0 + l31;
#pragma unroll
    for (int r = 0; r < 16; ++r) {
      float v0 = s0[r] * scale, v1 = s1[r] * scale;
      if (needmask) {
        int krow = (r & 3) + 8 * (r >> 2) + 4 * hh;
        if (kb + krow > qg)      v0 = -1e30f;
        if (kb + 32 + krow > qg) v1 = -1e30f;
      }
      p0[r] = v0; p1[r] = v1;
    }
    float t = fmaxf(p0[0], p1[0]);
#pragma unroll
    for (int r = 1; r < 16; ++r) t = fmaxf(t, fmaxf(p0[r], p1[r]));
    t = fmaxf(t, __shfl_xor(t, 32));
    if (!__all(t - m_run <= 8.0f)) {     // T13 defer-max
      float mnew = fmaxf(m_run, t);
      float fac = vexp2((m_run - mnew) * LOG2E);
      m_run = mnew;
      l_run *= fac;
#pragma unroll
      for (int dt = 0; dt < 4; ++dt)
#pragma unroll
        for (int r = 0; r < 16; ++r) acc_o[dt][r] *= fac;
    }
    float psum = 0.f;
#pragma unroll
    for (int r = 0; r < 16; ++r) {
      p0[r] = vexp2((p0[r] - m_run) * LOG2E); psum += p0[r];
      p1[r] = vexp2((p1[r] - m_run) * LOG2E); psum += p1[r];
    }
    psum += __shfl_xor(psum, 32);
    l_run += psum;
    bf16x8 paf[4];
#pragma unroll
    for (int kstep = 0; kstep < 4; ++kstep) {
      const float* p = (kstep < 2) ? p0 : p1;
      const int base = (kstep & 1) * 8;
      unsigned a0 = cvtpk(p[base + 0], p[base + 1]);
      unsigned b0 = cvtpk(p[base + 4], p[base + 5]);
      plswap(a0, b0);
      unsigned a1 = cvtpk(p[base + 2], p[base + 3]);
      unsigned b1 = cvtpk(p[base + 6], p[base + 7]);
      plswap(a1, b1);
      u32x4 pw; pw[0] = a0; pw[1] = a1; pw[2] = b0; pw[3] = b1;
      paf[kstep] = __builtin_bit_cast(bf16x8, pw);
    }
    __builtin_amdgcn_s_setprio(1);
#pragma unroll
    for (int dt = 0; dt < 4; ++dt) {
      int vrow = dt * 16 + (l31 >> 1);
#pragma unroll
      for (int kstep = 0; kstep < 4; ++kstep) {
        int slot = ((l31 & 1) * 8 + kstep * 2 + hh) ^ (vrow & 15);
        bf16x8 vf = *(const bf16x8*)(Vb + vrow * 256 + slot * 16);
        acc_o[dt] = __builtin_amdgcn_mfma_f32_32x32x16_bf16(vf, paf[kstep], acc_o[dt], 0, 0, 0);
      }
    }
    __builtin_amdgcn_s_setprio(0);
  };

  stageKV(0, 0);
  __syncthreads();

  int cur = 0;
  for (int kbi = 0; kbi <= qb_b; ++kbi) {
    int kb = kbi * 64;
    if (kbi < qb_b) stageKV(kb + 64, cur ^ 1);
    if (isB || kbi <= qb_a) compute_unit(kb, cur);
    __syncthreads();
    cur ^= 1;
  }

  float inv_l = 1.0f / l_run;
  bf16* orow = attn + (size_t)(unit_q0 + l31) * 4096 + qcol;
#pragma unroll
  for (int dt = 0; dt < 4; ++dt)
#pragma unroll
    for (int r = 0; r < 16; ++r) {
      int d = dt * 32 + (r & 3) + 8 * (r >> 2) + 4 * hh;
      orow[d] = (bf16)(acc_o[dt][r] * inv_l);
    }
}

extern "C" void kernel_launch(void* const* d_in, const int* in_sizes, int n_in,
                              void* d_out, int out_size, void* d_ws, size_t ws_size,
                              hipStream_t stream) {
  const float* X  = (const float*)d_in[0];
  const float* Wq = (const float*)d_in[1];
  const float* Wk = (const float*)d_in[2];
  const float* Wv = (const float*)d_in[3];
  const float* Wo = (const float*)d_in[4];
  float* out = (float*)d_out;

  const size_t XB_OFF  = 0;
  const size_t WT_OFF  = 16777216;
  const size_t VT_OFF  = WT_OFF + 33554432;       // inside Wt region, past Wo^T
  const size_t QKV_OFF = 16777216 + 50331648;
  if (ws_size < (size_t)92274688) return;

  char* ws = (char*)d_ws;
  bf16* Xb    = (bf16*)(ws + XB_OFF);
  bf16* Wt    = (bf16*)(ws + WT_OFF);
  bf16* Vt_g  = (bf16*)(ws + VT_OFF);
  bf16* QKV   = (bf16*)(ws + QKV_OFF);
  bf16* attnb = Xb;  // reuse after gemm1 consumed Xb

  // 1. cast hidden states
  cast_f32_bf16<<<2048, 256, 0, stream>>>(X, Xb, SEQ * HID);
  // 2. merged Wq/Wk/Wv transpose-cast (one launch) -> Wt[6144][4096]
  transpose_wqkv<<<dim3(64, 96), 256, 0, stream>>>(Wq, Wk, Wv, Wt);
  // 3. fused QKV projection: [2048,4096] @ [4096,6144]
  gemm_bt<bf16><<<dim3(QKVN / 128, SEQ / 128), 256, 0, stream>>>(Xb, Wt, QKV, HID, QKVN);
  // 4. transpose-cast Wo (reuses Wt space) + transpose V into global [g][d][s]
  transpose_cast<<<dim3(4096 / 64, 4096 / 64), 256, 0, stream>>>(Wo, Wt, 4096, 0);
  transpose_v<<<dim3(SEQ / 32, 4, 8), 256, 0, stream>>>(QKV, Vt_g);
  // 5. causal GQA flash attention v6.2 (balanced pairs, raw v_exp)
  attn_kernel<<<512, 256, 0, stream>>>(QKV, Vt_g, attnb);
  // 6. output projection -> f32 out: [2048,4096] @ [4096,4096]
  gemm_bt<float><<<dim3(4096 / 128, SEQ / 128), 256, 0, stream>>>(attnb, Wt, out, HID, 4096);
}